// Round 29
// baseline (38.847 us; speedup 1.0000x reference)
//
#include <hip/hip_runtime.h>
#include <hip/hip_bf16.h>

#define HH 192
#define WW 192
#define HOUT 190
#define NCH 64
#define XG_OFF 131072   // xg offset in d_ws (w2l occupies first 73,728 B)

typedef __attribute__((ext_vector_type(8))) short bf16x8;
typedef __attribute__((ext_vector_type(4))) float f32x4;

typedef const __attribute__((address_space(1))) void gv_t;
typedef __attribute__((address_space(3))) void lv_t;

static __device__ __forceinline__ ushort f2bf(float f) {
    __hip_bfloat16 h = __float2bfloat16(f);   // RNE
    return *reinterpret_cast<ushort*>(&h);
}

// W2L[tap][s][wv][g][col][j] — MFMA-A-fragment-ordered (R28, proven).
__global__ __launch_bounds__(256) void build_w2(const float* __restrict__ w,
                                                const int* __restrict__ conn,
                                                ushort* __restrict__ w2l) {
    int idx = blockIdx.x * 256 + threadIdx.x;   // (o, tap, kc) : 64*9*8 = 4608
    if (idx >= 4608) return;
    int o = idx / 72, rem = idx - o * 72, tap = rem >> 3, kc = rem & 7;
    int s = kc >> 2, g = kc & 3, wv = o >> 4, col = o & 15;
    ushort val[8];
    #pragma unroll
    for (int e = 0; e < 8; ++e) {
        int c = kc * 8 + e;
        float sum = 0.f;
        #pragma unroll
        for (int t = 0; t < 16; ++t) {
            int k = o * 16 + t;
            if (conn[k] == c) sum += w[k * 9 + tap];
        }
        val[e] = f2bf(sum);
    }
    uint4 v;
    v.x = (uint)val[0] | ((uint)val[1] << 16);
    v.y = (uint)val[2] | ((uint)val[3] << 16);
    v.z = (uint)val[4] | ((uint)val[5] << 16);
    v.w = (uint)val[6] | ((uint)val[7] << 16);
    size_t off = ((size_t)(tap * 2 + s)) * 2048 + wv * 512 + g * 128 + col * 8;
    *(uint4*)&w2l[off] = v;
}

// NCHW f32 -> K-split bf16 (R25, proven):
//   xg elem(b,r,kg,c,k) = (((b*192 + r)*8 + kg)*192 + c)*8 + k
__global__ __launch_bounds__(256) void ksplit_cast(const float* __restrict__ x,
                                                   ushort* __restrict__ xg) {
    const int tid = threadIdx.x;
    const int kg  = tid >> 5;            // 0..7
    const int c0  = tid & 31;
    const int r   = blockIdx.x / 6;
    const int seg = blockIdx.x % 6;
    const int b   = blockIdx.y;
    const int col = seg * 32 + c0;

    ushort t[8];
    #pragma unroll
    for (int k = 0; k < 8; ++k)
        t[k] = f2bf(x[((size_t)(b * NCH + kg * 8 + k) * HH + r) * WW + col]);

    uint4 v;
    v.x = (uint)t[0] | ((uint)t[1] << 16);
    v.y = (uint)t[2] | ((uint)t[3] << 16);
    v.z = (uint)t[4] | ((uint)t[5] << 16);
    v.w = (uint)t[6] | ((uint)t[7] << 16);
    ushort* dst = xg + ((((size_t)b * HH + r) * 8 + kg) * WW + col) * 8;
    *(uint4*)dst = v;
}

// Dense 64->64 3x3 conv via mfma_f32_16x16x32_bf16, operand-swapped.
// R29: staging via global_load_lds DMA from K-split xg — zero dest registers,
// all 6 DMA instrs/wave in flight regardless of regalloc (the serialization
// that capped every reg-staged variant cannot occur). LDS [kg][10r][18c][8ch].
__global__ __launch_bounds__(256, 3) void scm_mfma(
    const ushort* __restrict__ xg,
    const ushort* __restrict__ w2l,
    const float* __restrict__ bias,
    float* __restrict__ out)
{
    __shared__ ushort xt[1536 * 8];       // 24,576 B (1440 real 16B units + pad)

    const int tid  = threadIdx.x;
    const int wv   = tid >> 6;
    const int lane = tid & 63;
    const int col  = lane & 15;           // A-frag m (o) / B-frag n (pixel col)
    const int g    = lane >> 4;           // k-subgroup

    // Flattened grid (1152) + bijective XCD swizzle (1152 % 8 == 0).
    const int bid = blockIdx.x;
    const int lid = (bid & 7) * 144 + (bid >> 3);
    const int b      = lid / 288;
    const int tileid = lid % 288;
    const int ti0 = (tileid / 12) * 8;    // 24 row tiles
    const int tj0 = (tileid % 12) * 16;   // 12 col tiles

    // DMA source byte offsets: unit u = s*256+tid -> (kg, row, c) kg-major.
    // Pad units (u>=1440) and clamped rows/cols feed only LDS pad or outputs
    // >= 190 (discarded at store).
    int goff[6];
    #pragma unroll
    for (int s = 0; s < 6; ++s) {
        int u = s * 256 + tid;
        int kg = u / 180;  int rem = u - kg * 180;
        int row = rem / 18; int c = rem - row * 18;
        if (kg > 7) { kg = 7; row = 9; c = 17; }
        int gr = ti0 + row; if (gr > 191) gr = 191;
        int gc = tj0 + c;   if (gc > 191) gc = 191;
        goff[s] = ((((b * HH + gr) * 8 + kg) * WW + gc) * 8) * 2;
    }

    // ---- stage: 6 DMA instrs (16B/lane), W2 s=0 fragments fly underneath.
    const char* xgb = (const char*)xg;
    #pragma unroll
    for (int s = 0; s < 6; ++s)
        __builtin_amdgcn_global_load_lds((gv_t*)(xgb + goff[s]),
                                         (lv_t*)((char*)xt + s * 4096 + wv * 1024),
                                         16, 0, 0);

    const ushort* bpl = w2l + wv * 512 + g * 128 + col * 8;  // lane-contig layout
    bf16x8 Bs[9];
    bf16x8 fA[10], fB[10];

#define LOADB(s) do {                                                          \
        _Pragma("unroll")                                                      \
        for (int _tap = 0; _tap < 9; ++_tap)                                   \
            Bs[_tap] = *(const bf16x8*)(bpl + (_tap * 2 + (s)) * 2048);        \
    } while (0)

    LOADB(0);
    asm volatile("s_waitcnt vmcnt(0)" ::: "memory");
    __syncthreads();

    // ---- compute: fragment (R,kw,s) at ap0 + s*11520 + R*288 + kw*16 bytes.
    // 16 col-lanes contiguous 256B; g-groups 2880B apart -> 2-way (free).
    f32x4 acc[8];
    #pragma unroll
    for (int i = 0; i < 8; ++i) acc[i] = (f32x4){0.f, 0.f, 0.f, 0.f};

    const char* ap0 = (const char*)xt + (g * 180 + col) * 16;

#define LOADF(F, s, kw) do {                                                   \
        _Pragma("unroll")                                                      \
        for (int _R = 0; _R < 10; ++_R)                                        \
            F[_R] = *(const bf16x8*)(ap0 + (s) * 11520 + _R * 288 + (kw) * 16);\
    } while (0)

#define MFMA24(F, kw) do {                                                     \
        _Pragma("unroll")                                                      \
        for (int _Mt = 0; _Mt < 8; ++_Mt) {                                    \
            acc[_Mt] = __builtin_amdgcn_mfma_f32_16x16x32_bf16(Bs[kw],     F[_Mt],     acc[_Mt], 0, 0, 0); \
            acc[_Mt] = __builtin_amdgcn_mfma_f32_16x16x32_bf16(Bs[3+(kw)], F[_Mt + 1], acc[_Mt], 0, 0, 0); \
            acc[_Mt] = __builtin_amdgcn_mfma_f32_16x16x32_bf16(Bs[6+(kw)], F[_Mt + 2], acc[_Mt], 0, 0, 0); \
        }                                                                      \
    } while (0)

    LOADF(fA, 0, 0);
    LOADF(fB, 0, 1);  MFMA24(fA, 0);     // fB's reads fly under fA's MFMAs
    LOADF(fA, 0, 2);  MFMA24(fB, 1);
    LOADF(fB, 1, 0);  MFMA24(fA, 2);
    LOADB(1);                             // Bs for s=1
    LOADF(fA, 1, 1);  MFMA24(fB, 0);
    LOADF(fB, 1, 2);  MFMA24(fA, 1);
    MFMA24(fB, 2);

#undef LOADB
#undef LOADF
#undef MFMA24

    // ---- epilogue: D col = lane&15 = pixel col (contiguous); D row = o-quad.
    const int pcol = tj0 + col;
    const int obase = 16 * wv + 4 * g;
    float bv[4];
    #pragma unroll
    for (int reg = 0; reg < 4; ++reg) bv[reg] = bias[obase + reg];

    if (pcol < HOUT) {
        #pragma unroll
        for (int Mt = 0; Mt < 8; ++Mt) {
            const int row = ti0 + Mt;
            if (row < HOUT) {
                float* rp = out + ((size_t)(b * NCH + obase) * HOUT + row) * HOUT + pcol;
                #pragma unroll
                for (int reg = 0; reg < 4; ++reg)
                    rp[(size_t)reg * HOUT * HOUT] = acc[Mt][reg] + bv[reg];
            }
        }
    }
}

extern "C" void kernel_launch(void* const* d_in, const int* in_sizes, int n_in,
                              void* d_out, int out_size, void* d_ws, size_t ws_size,
                              hipStream_t stream) {
    const float* x       = (const float*)d_in[0];
    const float* weight  = (const float*)d_in[1];
    const float* bias    = (const float*)d_in[2];
    const int*   conn_in = (const int*)d_in[3];
    // d_in[4] = conn_out (implicit: k -> k/16)

    ushort* w2l = (ushort*)d_ws;                          // 73,728 B
    ushort* xg  = (ushort*)((char*)d_ws + XG_OFF);        // 18.9 MB K-split bf16

    ksplit_cast<<<dim3(6 * HH, 4), dim3(256), 0, stream>>>(x, xg);
    build_w2<<<dim3(18), dim3(256), 0, stream>>>(weight, conn_in, w2l);

    scm_mfma<<<dim3(1152), dim3(256), 0, stream>>>(xg, w2l, bias, (float*)d_out);
}